// Round 4
// baseline (585.009 us; speedup 1.0000x reference)
//
#include <hip/hip_runtime.h>
#include <hip/hip_bf16.h>

// Problem dims (fixed): B=64, Te=1024, De=Dd=H=1024.
#define B_  64
#define TE  1024
#define K_  1024
#define HH  1024
#define MM  (B_ * TE)

typedef __bf16 bf16x8 __attribute__((ext_vector_type(8)));
typedef __bf16 bf16x4 __attribute__((ext_vector_type(4)));
typedef float  f32x4  __attribute__((ext_vector_type(4)));

__device__ __forceinline__ float fast_tanh(float x) {
    // tanh(x) = sign(x) * (1 - e^{-2|x|}) / (1 + e^{-2|x|}); branch-free, no overflow.
    float ax = __builtin_fabsf(x);
    float t  = __expf(-2.0f * ax);
    float r  = (1.0f - t) * __builtin_amdgcn_rcpf(1.0f + t);
    return __builtin_copysignf(r, x);
}

// ---------------------------------------------------------------- prep: cvt(Ua_w) + Wa GEMV, merged
__global__ __launch_bounds__(256) void prep_kernel(const float* __restrict__ Ua_w,
                                                   __bf16* __restrict__ uawB,
                                                   const float* __restrict__ dec,
                                                   const float* __restrict__ Wa_w,
                                                   const float* __restrict__ Wa_b,
                                                   float* __restrict__ WaOut) {
    int bid = blockIdx.x, tid = threadIdx.x;
    if (bid < 256) {
        const long n4 = (long)HH * 1024 / 4;
        const float4* in4 = (const float4*)Ua_w;
        bf16x4* out4 = (bf16x4*)uawB;
        for (long j = bid * 256 + tid; j < n4; j += 65536) {
            float4 v = in4[j];
            bf16x4 o;
            o[0] = (__bf16)v.x; o[1] = (__bf16)v.y; o[2] = (__bf16)v.z; o[3] = (__bf16)v.w;
            out4[j] = o;
        }
        return;
    }
    int wb = bid - 256;
    int b = wb >> 4, hc = wb & 15;
    int wave = tid >> 6, lane = tid & 63;

    const float4* d4 = (const float4*)(dec + b * 1024);
    float4 dreg[4];
    #pragma unroll
    for (int j = 0; j < 4; j++) dreg[j] = d4[lane * 4 + j];

    #pragma unroll 4
    for (int i = 0; i < 16; i++) {
        int h = hc * 64 + wave * 16 + i;
        const float4* wr = (const float4*)(Wa_w + (long)h * 1024);
        float a = 0.0f;
        #pragma unroll
        for (int j = 0; j < 4; j++) {
            float4 v = wr[lane * 4 + j];
            a += v.x * dreg[j].x + v.y * dreg[j].y + v.z * dreg[j].z + v.w * dreg[j].w;
        }
        #pragma unroll
        for (int off = 32; off > 0; off >>= 1)
            a += __shfl_xor(a, off, 64);
        if (lane == 0) WaOut[b * 1024 + h] = a + Wa_b[h];
    }
}

// ---------------------------------------------------------------- fused score GEMM
// scores[m] += sum_h Va_w[h]*tanh(enc[m,:]·Ua_w[h,:] + Wa[b,h] + Ua_b[h])
// 128x256 tile, KT=32, double-buffered LDS (48 KB -> 2 blocks/CU at (256,2)).
// T3+T4: single raw s_barrier per K-step with COUNTED vmcnt -- B(t+1)'s
// global_load_lds stay in flight across the barrier; A(t+2) reg-prefetch in
// flight across the wait. Loads never drained to 0 in the main loop.
// KT=32 swizzle (bank-derived): phys slot p of row r holds k-seg p^((r>>1)&3)
// -> 2-way bank aliasing (free). Both-sides: pre-swizzled global src + swizzled
// ds_read; gload_lds dest linear (lane-consecutive 16B).
#define MT 128
#define NP 256
#define KT 32
#define NSTEP (K_ / KT)
#define SWZ(r) (((r) >> 1) & 3)

__global__ __launch_bounds__(256, 2) void score_gemm(
    const float* __restrict__ Af,    // [MM][1024] enc fp32
    __bf16* __restrict__ encB,       // [MM][1024] bf16 out (written by y==0 blocks)
    const __bf16* __restrict__ Bm,   // [1024][1024] Ua_w bf16
    const float* __restrict__ Wa,    // [64][1024]
    const float* __restrict__ Ua_b,  // [1024]
    const float* __restrict__ Va_w,  // [1024]
    float* __restrict__ scores)      // [MM], pre-zeroed, atomic accumulate
{
    __shared__ __bf16 sA[2][MT * KT];   // 2 x 8 KB
    __shared__ __bf16 sB[2][NP * KT];   // 2 x 16 KB
    __shared__ float sVa[NP];
    __shared__ float sWU[NP];

    const int tid  = threadIdx.x;
    const int wave = tid >> 6;
    const int lane = tid & 63;
    const int quad = lane >> 4;
    const int l16  = lane & 15;
    const int wm   = wave >> 1;      // 0..1 -> 64-row half
    const int wn   = wave & 1;       // 0..1 -> 128-col half

    // bid -> (x strip, y quarter); groups of 32 bids = 8 XCD slots x 4 y sharing x.
    const int bid = blockIdx.x;
    const int grp = bid >> 5;
    const int r5  = bid & 31;
    const int y   = r5 >> 3;
    const int x   = grp * 8 + (r5 & 7);

    const int rowBase = x * MT;
    const int colBase = y * NP;
    const int b       = rowBase >> 10;
    const bool wb     = (y == 0);    // this block writes the bf16 A strip

    if (tid < NP) {
        int h = colBase + tid;
        sVa[tid] = Va_w[h];
        sWU[tid] = Wa[b * 1024 + h] + Ua_b[h];
    }

    // A chunks (8 bf16 each): c = i*256+tid; r=c>>2; seg=(c&3)^SWZ(r). i=0..1
    int rrA[2], sgA[2];
    #pragma unroll
    for (int i = 0; i < 2; i++) {
        int c = i * 256 + tid;
        rrA[i] = c >> 2;
        sgA[i] = (c & 3) ^ SWZ(rrA[i]);
    }

    const long aBase = (long)rowBase * K_;
    const long bBase = (long)colBase * K_;

    float4 pre[2][2];

    auto loadA = [&](int tk) {       // 4 dwordx4 in flight
        int k = tk * KT;
        #pragma unroll
        for (int i = 0; i < 2; i++) {
            const float4* p = (const float4*)(Af + aBase + (long)rrA[i] * K_ + k + sgA[i] * 8);
            pre[i][0] = p[0]; pre[i][1] = p[1];
        }
    };
    auto cvtA = [&](__bf16* sAn, int tk) {   // pre -> bf16 -> LDS (+2 encB stores if wb)
        int k = tk * KT;
        #pragma unroll
        for (int i = 0; i < 2; i++) {
            bf16x8 v;
            v[0] = (__bf16)pre[i][0].x; v[1] = (__bf16)pre[i][0].y;
            v[2] = (__bf16)pre[i][0].z; v[3] = (__bf16)pre[i][0].w;
            v[4] = (__bf16)pre[i][1].x; v[5] = (__bf16)pre[i][1].y;
            v[6] = (__bf16)pre[i][1].z; v[7] = (__bf16)pre[i][1].w;
            *(bf16x8*)(sAn + (i * 256 + tid) * 8) = v;
            if (wb)
                *(bf16x8*)(encB + aBase + (long)rrA[i] * K_ + k + sgA[i] * 8) = v;
        }
    };
    auto stageB = [&](__bf16* sBn, int tk) { // 4 gload_lds, linear dest (lane x 16B)
        int k = tk * KT;
        #pragma unroll
        for (int i = 0; i < 4; i++) {
            int c = i * 256 + tid;
            int r = c >> 2;
            int seg = (c & 3) ^ SWZ(r);
            __builtin_amdgcn_global_load_lds(
                (const __attribute__((address_space(1))) unsigned int*)(Bm + bBase + (long)r * K_ + k + seg * 8),
                (__attribute__((address_space(3))) unsigned int*)(sBn + c * 8), 16, 0, 0);
        }
    };

    f32x4 acc[4][8] = {};            // [m-subtile s][n-subtile t8]

    auto compute = [&](const __bf16* sAc, const __bf16* sBc) {
        bf16x8 bfr[8];
        #pragma unroll
        for (int t8 = 0; t8 < 8; t8++) {
            int r = wn * 128 + t8 * 16 + l16;
            int slot = quad ^ SWZ(r);
            bfr[t8] = *(const bf16x8*)(sBc + r * KT + slot * 8);
        }
        #pragma unroll
        for (int s = 0; s < 4; s++) {
            int r = wm * 64 + s * 16 + l16;
            int slot = quad ^ SWZ(r);
            bf16x8 af = *(const bf16x8*)(sAc + r * KT + slot * 8);
            #pragma unroll
            for (int t8 = 0; t8 < 8; t8++)
                acc[s][t8] = __builtin_amdgcn_mfma_f32_16x16x32_bf16(af, bfr[t8], acc[s][t8], 0, 0, 0);
        }
    };

    // ---- prologue: tiles 0 and 1 staged, A(1) in regs -------------
    loadA(0);                        // [A0:4]
    stageB(sB[0], 0);                // [B0:4]
    cvtA(sA[0], 0);                  // waits A0 (compiler); [S0:2 if wb]
    loadA(1);                        // [A1:4]
    stageB(sB[1], 1);                // [B1:4]
    // B0 done <=> outstanding <= A1+B1 (+S handled: stores older, retire first)
    asm volatile("s_waitcnt vmcnt(8) lgkmcnt(0)" ::: "memory");
    __builtin_amdgcn_sched_barrier(0);
    __builtin_amdgcn_s_barrier();
    asm volatile("" ::: "memory");

    // ---- main loop: 1 counted barrier per step -------------------
    // Invariant at top of iter t: sA/sB[t&1] ready; pre=A(t+1); B(t+1) in flight.
    #pragma unroll 2
    for (int t = 0; t < NSTEP - 2; ++t) {
        const int cur = t & 1, nxt = cur ^ 1;
        compute(sA[cur], sB[cur]);
        cvtA(sA[nxt], t + 1);        // ds_writes; compiler waits pre=A(t+1)
        loadA(t + 2);                // 4 newest outstanding
        // drain B(t+1) (+stores), keep A(t+2) in flight:
        asm volatile("s_waitcnt vmcnt(4) lgkmcnt(0)" ::: "memory");
        __builtin_amdgcn_sched_barrier(0);
        __builtin_amdgcn_s_barrier();
        asm volatile("" ::: "memory");
        stageB(sB[cur], t + 2);      // into just-freed buffer; lands during iter t+1
    }
    // ---- t = NSTEP-2: no more prefetches -------------------------
    {
        const int cur = (NSTEP - 2) & 1, nxt = cur ^ 1;
        compute(sA[cur], sB[cur]);
        cvtA(sA[nxt], NSTEP - 1);
        asm volatile("s_waitcnt vmcnt(0) lgkmcnt(0)" ::: "memory");
        __builtin_amdgcn_sched_barrier(0);
        __builtin_amdgcn_s_barrier();
        asm volatile("" ::: "memory");
    }
    // ---- t = NSTEP-1 ---------------------------------------------
    compute(sA[(NSTEP - 1) & 1], sB[(NSTEP - 1) & 1]);

    // Epilogue. C/D layout: row = quad*4 + reg, col = l16.
    float rs[4][4] = {};
    #pragma unroll
    for (int s = 0; s < 4; s++)
        #pragma unroll
        for (int t = 0; t < 8; t++) {
            int hl = wn * 128 + t * 16 + l16;
            float va = sVa[hl], wu = sWU[hl];
            #pragma unroll
            for (int r = 0; r < 4; r++)
                rs[s][r] += va * fast_tanh(acc[s][t][r] + wu);
        }

    #pragma unroll
    for (int s = 0; s < 4; s++)
        #pragma unroll
        for (int r = 0; r < 4; r++) {
            float v = rs[s][r];
            v += __shfl_xor(v, 1, 64);
            v += __shfl_xor(v, 2, 64);
            v += __shfl_xor(v, 4, 64);
            v += __shfl_xor(v, 8, 64);
            if (l16 == 0)
                atomicAdd(&scores[rowBase + wm * 64 + s * 16 + quad * 4 + r], v);
        }
}

// ---------------------------------------------------------------- softmax over Te, in place
__global__ __launch_bounds__(256) void softmax_kernel(float* __restrict__ s) {
    __shared__ float red[8];
    int b = blockIdx.x, tid = threadIdx.x;
    int wave = tid >> 6, lane = tid & 63;
    float4* row = (float4*)(s + b * 1024);
    float4 v = row[tid];
    float m = fmaxf(fmaxf(v.x, v.y), fmaxf(v.z, v.w));
    #pragma unroll
    for (int off = 32; off > 0; off >>= 1)
        m = fmaxf(m, __shfl_xor(m, off, 64));
    if (lane == 0) red[wave] = m;
    __syncthreads();
    m = fmaxf(fmaxf(red[0], red[1]), fmaxf(red[2], red[3]));
    v.x = expf(v.x - m); v.y = expf(v.y - m); v.z = expf(v.z - m); v.w = expf(v.w - m);
    float sum = v.x + v.y + v.z + v.w;
    #pragma unroll
    for (int off = 32; off > 0; off >>= 1)
        sum += __shfl_xor(sum, off, 64);
    if (lane == 0) red[4 + wave] = sum;
    __syncthreads();
    float inv = 1.0f / (red[4] + red[5] + red[6] + red[7]);
    v.x *= inv; v.y *= inv; v.z *= inv; v.w *= inv;
    row[tid] = v;
}

// ---------------------------------------------------------------- context partials (atomic-free)
__global__ __launch_bounds__(256) void context_partial(const __bf16* __restrict__ enc,
                                                       const float* __restrict__ w,
                                                       float* __restrict__ pb) {
    __shared__ float red[2][128][8];     // 8 KB
    int b = blockIdx.x, ec = blockIdx.y, tid = threadIdx.x;
    int eo = tid >> 7;
    int dc = tid & 127;
    const bf16x8* enc8 = (const bf16x8*)(enc + ((long)b * 1024 + ec * 128) * 1024);
    const float* wrow = w + b * 1024 + ec * 128;
    float acc[8] = {};
    #pragma unroll 4
    for (int e = eo; e < 128; e += 2) {
        float we = wrow[e];
        bf16x8 v = enc8[e * 128 + dc];
        #pragma unroll
        for (int j = 0; j < 8; j++) acc[j] += we * (float)v[j];
    }
    #pragma unroll
    for (int j = 0; j < 8; j++) red[eo][dc][j] = acc[j];
    __syncthreads();
    if (eo == 0) {
        float* o = pb + ((long)(b * 8 + ec)) * 1024 + dc * 8;
        #pragma unroll
        for (int j = 0; j < 8; j++) o[j] = red[0][dc][j] + red[1][dc][j];
    }
}

__global__ void context_reduce(const float* __restrict__ pb, float* __restrict__ out) {
    int b = blockIdx.x, tid = threadIdx.x;
    const f32x4* p4 = (const f32x4*)pb;
    f32x4 s = {0.f, 0.f, 0.f, 0.f};
    #pragma unroll
    for (int ec = 0; ec < 8; ec++)
        s += p4[(b * 8 + ec) * 256 + tid];
    ((f32x4*)out)[b * 256 + tid] = s;
}

// ----------------------------------------------------------------
extern "C" void kernel_launch(void* const* d_in, const int* in_sizes, int n_in,
                              void* d_out, int out_size, void* d_ws, size_t ws_size,
                              hipStream_t stream) {
    (void)in_sizes; (void)n_in; (void)ws_size;
    const float* enc   = (const float*)d_in[0];
    const float* dec   = (const float*)d_in[1];
    const float* Wa_w  = (const float*)d_in[2];
    const float* Wa_b  = (const float*)d_in[3];
    const float* Ua_w  = (const float*)d_in[4];
    const float* Ua_b  = (const float*)d_in[5];
    const float* Va_w  = (const float*)d_in[6];
    // d_in[7] = Va_b: softmax-invariant -> dropped.
    float* out = (float*)d_out;

    char* w = (char*)d_ws;
    __bf16* encB = (__bf16*)w;  w += (size_t)MM * 1024 * 2;
    __bf16* uawB = (__bf16*)w;  w += (size_t)HH * 1024 * 2;
    float* WaBuf = (float*)w;   w += (size_t)B_ * HH * 4;
    float* scores = (float*)w;  w += (size_t)MM * 4;
    float* pb = (float*)w;      w += (size_t)B_ * 8 * 1024 * 4;

    hipMemsetAsync(scores, 0, (size_t)MM * 4, stream);
    prep_kernel<<<dim3(256 + B_ * 16), 256, 0, stream>>>(Ua_w, uawB, dec, Wa_w, Wa_b, WaBuf);
    score_gemm<<<dim3((MM / MT) * (HH / NP)), 256, 0, stream>>>(enc, encB, uawB, WaBuf, Ua_b, Va_w, scores);
    softmax_kernel<<<dim3(B_), 256, 0, stream>>>(scores);
    context_partial<<<dim3(B_, 8), 256, 0, stream>>>(encB, scores, pb);
    context_reduce<<<dim3(B_), 256, 0, stream>>>(pb, out);
}